// Round 5
// baseline (493.904 us; speedup 1.0000x reference)
//
#include <hip/hip_runtime.h>
#include <hip/hip_bf16.h>
#include <math.h>

// Problem constants (B,S,D) = (4,4096,1024)
#define BDIM 4
#define SDIM 4096
#define DDIM 1024
#define MROWS (BDIM*SDIM)      // 16384
#define EPS 1e-6f
#define NCHUNK 64              // chunks along S
#define LCHUNK 64              // chunk length (NCHUNK*LCHUNK == SDIM)

typedef _Float16 f16_t;
typedef _Float16 f16x2_t __attribute__((ext_vector_type(2)));
typedef _Float16 f16x4_t __attribute__((ext_vector_type(4)));
typedef _Float16 f16x8_t __attribute__((ext_vector_type(8)));     // MFMA A/B frag (4 VGPRs)
typedef float    f32x4_t __attribute__((ext_vector_type(4)));     // MFMA C/D frag

// async global->LDS, 16B per lane (dest = wave-uniform base + lane*16)
__device__ __forceinline__ void gload16(const void* g, void* l) {
    __builtin_amdgcn_global_load_lds(
        (const __attribute__((address_space(1))) unsigned int*)g,
        (__attribute__((address_space(3))) unsigned int*)l, 16, 0, 0);
}

// ---------------------------------------------------------------------------
// Guard-fail fill (encodes ws_size MB as output on too-small workspace)
// ---------------------------------------------------------------------------
__global__ __launch_bounds__(256) void fill_kernel(float* __restrict__ out,
                                                   int n, float val)
{
    const int i = blockIdx.x * 256 + threadIdx.x;
    if (i < n) out[i] = val;
}

// ---------------------------------------------------------------------------
// RMSNorm: one block per row of D=1024; outputs fp16 xn.
// ---------------------------------------------------------------------------
__global__ __launch_bounds__(256) void rmsnorm_kernel(
    const float* __restrict__ x, const float* __restrict__ scale,
    f16_t* __restrict__ xn)
{
    const int row = blockIdx.x;
    const int tid = threadIdx.x;
    const float4 v = reinterpret_cast<const float4*>(x + (size_t)row * DDIM)[tid];
    float ss = v.x*v.x + v.y*v.y + v.z*v.z + v.w*v.w;
    #pragma unroll
    for (int off = 32; off > 0; off >>= 1)
        ss += __shfl_down(ss, off, 64);
    __shared__ float red[4];
    if ((tid & 63) == 0) red[tid >> 6] = ss;
    __syncthreads();
    ss = red[0] + red[1] + red[2] + red[3];
    const float inv = rsqrtf(ss * (1.0f / DDIM) + EPS);
    const float4 sc = reinterpret_cast<const float4*>(scale)[tid];
    f16x4_t o;
    o.x = (f16_t)(v.x * inv * sc.x);
    o.y = (f16_t)(v.y * inv * sc.y);
    o.z = (f16_t)(v.z * inv * sc.z);
    o.w = (f16_t)(v.w * inv * sc.w);
    reinterpret_cast<f16x4_t*>(xn + (size_t)row * DDIM)[tid] = o;
}

// ---------------------------------------------------------------------------
// Weight prep (merged): 5 square weights W[K][N] f32 -> WT[N][K] f16.
// blockIdx.z selects the weight; destination offsets {0,1,2,3,6}*WSZ
// (wo goes to slot 6; slots 4..5 belong to WTa).
// ---------------------------------------------------------------------------
__global__ __launch_bounds__(256) void transpose5_kernel(
    const float* __restrict__ w0, const float* __restrict__ w1,
    const float* __restrict__ w2, const float* __restrict__ w3,
    const float* __restrict__ w4, f16_t* __restrict__ WT)
{
    const int K = DDIM, N = DDIM;
    const int z = blockIdx.z;
    const float* W = (z == 0) ? w0 : (z == 1) ? w1 : (z == 2) ? w2
                   : (z == 3) ? w3 : w4;
    const int zoff = (z == 4) ? 6 : z;   // wo -> slot 6 (WTa occupies 4..5)
    f16_t* dst = WT + (size_t)zoff * DDIM * DDIM;
    __shared__ float t[32][33];
    const int kb = blockIdx.y * 32;
    const int nb = blockIdx.x * 32;
    const int r  = threadIdx.x >> 3;
    const int c0 = (threadIdx.x & 7) << 2;
    const float4 v = *reinterpret_cast<const float4*>(&W[(size_t)(kb + r) * N + nb + c0]);
    t[r][c0 + 0] = v.x; t[r][c0 + 1] = v.y; t[r][c0 + 2] = v.z; t[r][c0 + 3] = v.w;
    __syncthreads();
    f16x4_t o;
    o.x = (f16_t)t[c0 + 0][r];
    o.y = (f16_t)t[c0 + 1][r];
    o.z = (f16_t)t[c0 + 2][r];
    o.w = (f16_t)t[c0 + 3][r];
    *reinterpret_cast<f16x4_t*>(&dst[(size_t)(nb + r) * K + kb + c0]) = o;
}

// ---------------------------------------------------------------------------
// Weight prep for wa: W[K][2048] f32 -> WTa[n][K] f16 with INTERLEAVED rows:
// output row n corresponds to original column (n>>1) + (n&1)*1024.
// ---------------------------------------------------------------------------
__global__ __launch_bounds__(256) void transpose_a_kernel(
    const float* __restrict__ W, f16_t* __restrict__ WT)
{
    const int K = DDIM, N = 2 * DDIM;
    __shared__ float t[32][33];
    const int kb = blockIdx.y * 32;
    const int nb = blockIdx.x * 32;
    const int r  = threadIdx.x >> 3;
    const int c0 = (threadIdx.x & 7) << 2;
    const int base = (c0 < 16) ? ((nb >> 1) + c0) : (DDIM + (nb >> 1) + c0 - 16);
    const float4 v = *reinterpret_cast<const float4*>(&W[(size_t)(kb + r) * N + base]);
    t[r][c0 + 0] = v.x; t[r][c0 + 1] = v.y; t[r][c0 + 2] = v.z; t[r][c0 + 3] = v.w;
    __syncthreads();
    const int rr  = threadIdx.x >> 3;
    const int cc0 = (threadIdx.x & 7) << 2;
    const int ctile = (rr >> 1) + (rr & 1) * 16;
    f16x4_t o;
    o.x = (f16_t)t[cc0 + 0][ctile];
    o.y = (f16_t)t[cc0 + 1][ctile];
    o.z = (f16_t)t[cc0 + 2][ctile];
    o.w = (f16_t)t[cc0 + 3][ctile];
    *reinterpret_cast<f16x4_t*>(&WT[(size_t)(nb + rr) * K + kb + cc0]) = o;
}

// ---------------------------------------------------------------------------
// fp16 MFMA GEMM, 256x256 tile, phase-interleaved counted-vmcnt schedule
// (T3+T4+T5), 4-deep LDS ring, BK=32.
//
// R5 deltas vs R3 (which hit 26% MfmaUtil):
//  - REMOVED per-phase asm lgkmcnt(0) + sched_barrier(0). Rule #18 applies
//    only to inline-asm ds_read; ours are compiler-emitted, so the pins were
//    pure order-pinning (m141: order-pinning collapses 874->510 TF). Without
//    them the compiler emits fine-grained lgkmcnt(4/3/1/0) interleave
//    (m97-verified near-optimal). asm vmcnt stays: global_load_lds has no
//    dest register, so only asm can order it. Ring safety unchanged: each
//    phase's MFMA consumes its reads before the iteration-end barrier, so
//    reads complete before the next stage overwrites that buffer.
//  - ADDED T1 bijective XCD block swizzle (R4-proven: FETCH 142->94 MB).
//
// LDS: within-quad chunk swizzle (R3-proven: conflicts 9.4M -> 0); staging
// quads read contiguous 64B global segments (R0-grade coalescing).
//   - 512 threads = 8 waves (2 M x 4 N); per-wave output 128x64 (acc[8][4]).
//   - As/Bs each 4 ring buffers x 16 KiB = 128 KiB total.
//   - Boundary wait vmcnt(8): tiles {t+2,t+3} stay in flight; tile t+1
//     guaranteed landed. Main loop NEVER drains vmcnt to 0 (T4).
// C[M,N] = A[M,K] @ BT[N,K]^T
// MODE 0: C(f32)  = A@B                               (final GEMM)
// MODE 2: C(f16)  = f16(C * (A@B))                    (kv = k*v)
// MODE 4: a-polar fused -> f16: val*sigmoid(|a|)/|a|  (interleaved re/im)
// MODE 5: multi-dest f16: N=3072 -> q (Cv), k (Cv2), g (Cv3) by bn
// ---------------------------------------------------------------------------
template <int MODE>
__global__ __launch_bounds__(512, 2) void mfma_gemm_kernel(
    const f16_t* __restrict__ A, const f16_t* __restrict__ BT,
    void* __restrict__ Cv, void* __restrict__ Cv2, void* __restrict__ Cv3,
    int M, int N, int K)
{
    __shared__ __align__(16) f16_t As[4 * 256 * 32];   // 4 bufs x 16 KiB
    __shared__ __align__(16) f16_t Bs[4 * 256 * 32];

    const int tid  = threadIdx.x;
    const int wave = tid >> 6;
    const int lane = tid & 63;

    // ---- T1: XCD-aware bijective block swizzle ---------------------------
    const int gx  = gridDim.x;
    const int nwg = gx * gridDim.y;
    const int lid = blockIdx.y * gx + blockIdx.x;
    const int cpx = nwg >> 3;                  // nwg % 8 == 0 for all grids
    const int vid = (lid & 7) * cpx + (lid >> 3);
    const int bm = (vid / gx) * 256;
    const int bn = (vid % gx) * 256;

    const int wm = (wave >> 2) * 128;   // wave row block (0 or 128)
    const int wn = (wave & 3) * 64;     // wave col block (0/64/128/192)

    // ---- staging source: quad-contiguous, within-quad chunk swizzle ------
    const int srow = tid >> 2;                                // 0..127
    const int scol = (((tid & 3) ^ ((tid >> 3) & 3)) << 3);   // elements
    const f16_t* Ag0 = A  + (size_t)(bm + srow) * K + scol;
    const f16_t* Ag1 = A  + (size_t)(bm + 128 + srow) * K + scol;
    const f16_t* Bg0 = BT + (size_t)(bn + srow) * K + scol;
    const f16_t* Bg1 = BT + (size_t)(bn + 128 + srow) * K + scol;
    f16_t* Al = As + tid * 8;            // + buf*8192 (+4096 for instr 1)
    f16_t* Bl = Bs + tid * 8;

    // ---- frag read offsets: swizzled, conflict-free ----------------------
    const int fm = lane & 15;
    const int fc = (lane >> 4) ^ ((lane >> 1) & 3);
    int aoff[8], boff[4];                // element offsets within a buffer
    #pragma unroll
    for (int i = 0; i < 8; ++i) aoff[i] = ((wm >> 4) + i) * 512 + fm * 32 + fc * 8;
    #pragma unroll
    for (int j = 0; j < 4; ++j) boff[j] = ((wn >> 4) + j) * 512 + fm * 32 + fc * 8;

    f32x4_t acc[8][4] = {};

    const int NT = K >> 5;               // 32 K-tiles

    // prologue: stage tiles 0..2 (12 gload instrs)
    #pragma unroll
    for (int p = 0; p < 3; ++p) {
        gload16(Ag0 + p * 32, Al + p * 8192);
        gload16(Ag1 + p * 32, Al + p * 8192 + 4096);
        gload16(Bg0 + p * 32, Bl + p * 8192);
        gload16(Bg1 + p * 32, Bl + p * 8192 + 4096);
    }
    asm volatile("s_waitcnt vmcnt(8)" ::: "memory");   // tile 0 landed
    __builtin_amdgcn_s_barrier();

    for (int t = 0; t < NT; ++t) {
        const f16_t* Ab = As + (t & 3) * 8192;
        const f16_t* Bb = Bs + (t & 3) * 8192;
        const int u  = t + 3;            // tile being staged
        const int sb = u & 3;            // its buffer (!= t&3 since 3%4 != 0)

        // ---------------- phase A: row-frags 0..3 x col-frags 0..3 --------
        if (u < NT) {
            gload16(Ag0 + u * 32, Al + sb * 8192);
            gload16(Bg0 + u * 32, Bl + sb * 8192);
        }
        f16x8_t af[4], bf[4];
        #pragma unroll
        for (int j = 0; j < 4; ++j)
            bf[j] = *reinterpret_cast<const f16x8_t*>(Bb + boff[j]);
        #pragma unroll
        for (int i = 0; i < 4; ++i)
            af[i] = *reinterpret_cast<const f16x8_t*>(Ab + aoff[i]);
        __builtin_amdgcn_s_barrier();
        __builtin_amdgcn_s_setprio(1);
        #pragma unroll
        for (int i = 0; i < 4; ++i)
            #pragma unroll
            for (int j = 0; j < 4; ++j)
                acc[i][j] = __builtin_amdgcn_mfma_f32_16x16x32_f16(
                    af[i], bf[j], acc[i][j], 0, 0, 0);
        __builtin_amdgcn_s_setprio(0);
        __builtin_amdgcn_s_barrier();

        // ---------------- phase B: row-frags 4..7 (bf reused in regs) -----
        if (u < NT) {
            gload16(Ag1 + u * 32, Al + sb * 8192 + 4096);
            gload16(Bg1 + u * 32, Bl + sb * 8192 + 4096);
        }
        #pragma unroll
        for (int i = 0; i < 4; ++i)
            af[i] = *reinterpret_cast<const f16x8_t*>(Ab + aoff[4 + i]);
        __builtin_amdgcn_s_barrier();
        __builtin_amdgcn_s_setprio(1);
        #pragma unroll
        for (int i = 0; i < 4; ++i)
            #pragma unroll
            for (int j = 0; j < 4; ++j)
                acc[4 + i][j] = __builtin_amdgcn_mfma_f32_16x16x32_f16(
                    af[i], bf[j], acc[4 + i][j], 0, 0, 0);
        __builtin_amdgcn_s_setprio(0);

        // ---------------- K-tile boundary: counted wait, never drains -----
        if (t < NT - 1) {
            if (t < NT - 3)       asm volatile("s_waitcnt vmcnt(8)" ::: "memory");
            else if (t == NT - 3) asm volatile("s_waitcnt vmcnt(4)" ::: "memory");
            else                  asm volatile("s_waitcnt vmcnt(0)" ::: "memory");
            __builtin_amdgcn_s_barrier();
        }
    }

    // epilogue: D row=(lane>>4)*4+reg, col=lane&15  (m89/m91-verified)
    const int erow = (lane >> 4) << 2;
    const int ecol = lane & 15;
    #pragma unroll
    for (int i = 0; i < 8; ++i) {
        #pragma unroll
        for (int j = 0; j < 4; ++j) {
            const int row0 = bm + wm + i * 16 + erow;
            const int col  = bn + wn + j * 16 + ecol;
            #pragma unroll
            for (int rg = 0; rg < 4; ++rg) {
                const size_t idx = (size_t)(row0 + rg) * N + col;
                const float val = acc[i][j][rg];
                if (MODE == 0) {
                    ((float*)Cv)[idx] = val;
                } else if (MODE == 2) {
                    f16_t* C = (f16_t*)Cv;
                    C[idx] = (f16_t)((float)C[idx] * val);
                } else if (MODE == 4) {
                    // adjacent lanes hold (re,im) of one channel
                    const float par = __shfl_xor(val, 1, 64);
                    const float re = (lane & 1) ? par : val;
                    const float im = (lane & 1) ? val : par;
                    const float r = sqrtf(re * re + im * im);
                    float outv;
                    if (r > 0.0f) {
                        const float sg = 1.0f / (1.0f + __expf(-r));
                        outv = val * (sg / r);
                    } else {
                        outv = (lane & 1) ? 0.0f : 0.5f;
                    }
                    ((f16_t*)Cv)[idx] = (f16_t)outv;
                } else {  // MODE 5
                    f16_t* dst = (bn < 1024) ? (f16_t*)Cv
                               : (bn < 2048) ? (f16_t*)Cv2 : (f16_t*)Cv3;
                    const size_t didx = (size_t)(row0 + rg) * DDIM + ((bn & 1023) + wn + j * 16 + ecol);
                    dst[didx] = (f16_t)val;
                }
            }
        }
    }
}

// ---------------------------------------------------------------------------
// Scan phase 1: per-(b,chunk,d) local scan; emit (A_prod, H_local) float4.
// a layout: [m][d] = f16x2 (re,im).
// ---------------------------------------------------------------------------
__global__ __launch_bounds__(256) void scan1_kernel(
    const f16x2_t* __restrict__ a2, const f16_t* __restrict__ kvb,
    float4* __restrict__ state)
{
    const int t = blockIdx.x * 256 + threadIdx.x;   // B*NCHUNK*D
    const int d = t & 1023;
    const int c = (t >> 10) & (NCHUNK - 1);
    const int b = t >> 16;
    size_t base  = ((size_t)(b * SDIM + c * LCHUNK)) * DDIM + d;
    float Ar = 1.0f, Ai = 0.0f, Hr = 0.0f, Hi = 0.0f;
    for (int s = 0; s < LCHUNK; ++s) {
        const f16x2_t av = a2[base];
        const float arr = (float)av.x;
        const float aii = (float)av.y;
        const float kv = (float)kvb[base];
        const float hr = arr * Hr - aii * Hi + kv;
        const float hi = arr * Hi + aii * Hr;
        Hr = hr; Hi = hi;
        const float nr = arr * Ar - aii * Ai;
        const float ni = arr * Ai + aii * Ar;
        Ar = nr; Ai = ni;
        base += DDIM;
    }
    state[t] = make_float4(Ar, Ai, Hr, Hi);
}

// ---------------------------------------------------------------------------
// Scan phase 2: wave-parallel chunk combine. Lane c holds chunk c's state;
// 6-step Hillis-Steele inclusive scan of (A,H)∘, then exclusive-shift -> carry.
// ---------------------------------------------------------------------------
__global__ __launch_bounds__(256) void scan2_kernel(
    const float4* __restrict__ state, float2* __restrict__ carry)
{
    const int t = blockIdx.x * 256 + threadIdx.x;   // B*D*64 threads
    const int c = t & 63;            // chunk index = lane
    const int ch = t >> 6;           // channel: b*1024+d
    const int d = ch & 1023;
    const int b = ch >> 10;
    const size_t idx = ((size_t)(b * NCHUNK + c)) * DDIM + d;
    const float4 st = state[idx];
    float Ar = st.x, Ai = st.y, Hr = st.z, Hi = st.w;
    #pragma unroll
    for (int off = 1; off < 64; off <<= 1) {
        const float pAr = __shfl_up(Ar, off, 64);
        const float pAi = __shfl_up(Ai, off, 64);
        const float pHr = __shfl_up(Hr, off, 64);
        const float pHi = __shfl_up(Hi, off, 64);
        if (c >= off) {
            // compose(earlier=(pA,pH), current=(A,H)): A·pA, A·pH + H
            const float nHr = Ar * pHr - Ai * pHi + Hr;
            const float nHi = Ar * pHi + Ai * pHr + Hi;
            const float nAr = Ar * pAr - Ai * pAi;
            const float nAi = Ar * pAi + Ai * pAr;
            Ar = nAr; Ai = nAi; Hr = nHr; Hi = nHi;
        }
    }
    // exclusive prefix: carry into chunk c = inclusive H at chunk c-1
    const float eHr = __shfl_up(Hr, 1, 64);
    const float eHi = __shfl_up(Hi, 1, 64);
    carry[idx] = make_float2(c == 0 ? 0.0f : eHr, c == 0 ? 0.0f : eHi);
}

// ---------------------------------------------------------------------------
// Scan phase 3: re-scan with carry; y(f16) = q * silu(g) * Re(h),
// written IN-PLACE over kv.
// ---------------------------------------------------------------------------
__global__ __launch_bounds__(256) void scan3_kernel(
    const f16x2_t* __restrict__ a2, f16_t* __restrict__ kvb,
    const f16_t* __restrict__ qb, const f16_t* __restrict__ gb,
    const float2* __restrict__ carry)
{
    const int t = blockIdx.x * 256 + threadIdx.x;   // B*NCHUNK*D
    const int d = t & 1023;
    const int c = (t >> 10) & (NCHUNK - 1);
    const int b = t >> 16;
    size_t base  = ((size_t)(b * SDIM + c * LCHUNK)) * DDIM + d;
    const float2 h0 = carry[t];
    float Hr = h0.x, Hi = h0.y;
    for (int s = 0; s < LCHUNK; ++s) {
        const f16x2_t av = a2[base];
        const float arr = (float)av.x;
        const float aii = (float)av.y;
        const float kv = (float)kvb[base];
        const float hr = arr * Hr - aii * Hi + kv;
        const float hi = arr * Hi + aii * Hr;
        Hr = hr; Hi = hi;
        const float qv = (float)qb[base];
        const float gv = (float)gb[base];
        const float silu = gv / (1.0f + __expf(-gv));
        kvb[base] = (f16_t)(qv * silu * Hr);
        base += DDIM;
    }
}

// ---------------------------------------------------------------------------
// kernel_launch
//
// Workspace layout (149 MB):
//   xn:  [SZ f16]   33.5MB — A operand; scan `state` (4MB) overlaps after death
//   kv:  [SZ f16]   33.5MB — k, then kv=k*v, then y (in-place in scan3)
//   a:   [SZ f16x2] 67MB   — interleaved (re,im) channel pairs
//   WT:  [7*WSZ f16] 14MB  — slots: 0=q 1=k 2=g 3=v 4..5=a(interleaved) 6=o;
//        `carry` (2MB) overlaps dead WTq after the projection GEMMs
// q,g (f16) live in the two halves of d_out until the final GEMM overwrites it.
// ---------------------------------------------------------------------------
extern "C" void kernel_launch(void* const* d_in, const int* in_sizes, int n_in,
                              void* d_out, int out_size, void* d_ws, size_t ws_size,
                              hipStream_t stream)
{
    const float* x        = (const float*)d_in[0];
    const float* wq       = (const float*)d_in[1];
    const float* wk       = (const float*)d_in[2];
    const float* wv       = (const float*)d_in[3];
    const float* wa       = (const float*)d_in[4];
    const float* wg       = (const float*)d_in[5];
    const float* wo       = (const float*)d_in[6];
    const float* rms_scale= (const float*)d_in[7];
    float* out = (float*)d_out;

    const size_t SZ = (size_t)MROWS * DDIM;   // 16,777,216 elements
    const size_t WSZ = (size_t)DDIM * DDIM;   // 1,048,576
    char* ws = (char*)d_ws;
    f16_t*   xn   = (f16_t*)ws;                        // SZ f16
    f16_t*   kv   = (f16_t*)(ws + SZ * 2);             // SZ f16
    f16x2_t* abuf = (f16x2_t*)(ws + SZ * 4);           // SZ f16x2
    f16_t*   WT   = (f16_t*)(ws + SZ * 8);             // 7*WSZ f16
    f16_t* WTv = WT + 3 * WSZ;
    f16_t* WTa = WT + 4 * WSZ;       // 2M elements (interleaved rows), slots 4..5
    f16_t* WTo = WT + 6 * WSZ;       // slot 6
    float4* state = (float4*)xn;     // overlaps dead xn (4MB)
    float2* carry = (float2*)WT;     // overlaps dead WTq (2MB)

    f16_t* qb = (f16_t*)d_out;       // q f16 in first half of d_out
    f16_t* gb = qb + SZ;             // g f16 in second half

    const size_t needed = SZ * 8 + 7 * WSZ * 2;
    if (ws_size < needed) {
        const float marker = (float)(ws_size >> 20);
        fill_kernel<<<(out_size + 255) / 256, 256, 0, stream>>>(out, out_size, marker);
        return;
    }

    // 1. RMSNorm -> f16 xn
    rmsnorm_kernel<<<MROWS, 256, 0, stream>>>(x, rms_scale, xn);

    // 2. Weight prep (2 launches)
    dim3 tblk(256);
    dim3 tg5(DDIM / 32, DDIM / 32, 5);
    transpose5_kernel<<<tg5, tblk, 0, stream>>>(wq, wk, wg, wv, wo, WT);
    dim3 tga(2 * DDIM / 32, DDIM / 32);
    transpose_a_kernel<<<tga, tblk, 0, stream>>>(wa, WTa);

    // 3. Projections (256^2-tile phase-interleaved GEMM, 512 threads)
    dim3 blk(512);
    dim3 gqkg(3 * DDIM / 256, MROWS / 256);   // (12,64) fused q,k,g
    dim3 g1(DDIM / 256, MROWS / 256);         // (4,64)
    dim3 g2(2 * DDIM / 256, MROWS / 256);     // (8,64)
    mfma_gemm_kernel<5><<<gqkg, blk, 0, stream>>>(xn, WT,  qb, kv, gb, MROWS, 3 * DDIM, DDIM);
    mfma_gemm_kernel<2><<<g1,   blk, 0, stream>>>(xn, WTv, kv, nullptr, nullptr, MROWS, DDIM, DDIM);   // kv = k*v
    mfma_gemm_kernel<4><<<g2,   blk, 0, stream>>>(xn, WTa, abuf, nullptr, nullptr, MROWS, 2 * DDIM, DDIM); // a

    // 4. chunked complex scan
    const int nscan = BDIM * NCHUNK * DDIM;   // 262144
    scan1_kernel<<<nscan / 256, 256, 0, stream>>>(abuf, kv, state);
    scan2_kernel<<<nscan / 256, 256, 0, stream>>>(state, carry);
    scan3_kernel<<<nscan / 256, 256, 0, stream>>>(abuf, kv, qb, gb, carry);

    // 5. out = y @ wo   (y lives in kv buffer)
    mfma_gemm_kernel<0><<<g1, blk, 0, stream>>>(kv, WTo, out, nullptr, nullptr, MROWS, DDIM, DDIM);
}

// Round 6
// 422.532 us; speedup vs baseline: 1.1689x; 1.1689x over previous
//
#include <hip/hip_runtime.h>
#include <hip/hip_bf16.h>
#include <math.h>

// Problem constants (B,S,D) = (4,4096,1024)
#define BDIM 4
#define SDIM 4096
#define DDIM 1024
#define MROWS (BDIM*SDIM)      // 16384
#define EPS 1e-6f
#define NCHUNK 64              // chunks along S
#define LCHUNK 64              // chunk length (NCHUNK*LCHUNK == SDIM)

typedef _Float16 f16_t;
typedef _Float16 f16x2_t __attribute__((ext_vector_type(2)));
typedef _Float16 f16x4_t __attribute__((ext_vector_type(4)));
typedef _Float16 f16x8_t __attribute__((ext_vector_type(8)));     // MFMA A/B frag (4 VGPRs)
typedef float    f32x4_t __attribute__((ext_vector_type(4)));     // MFMA C/D frag

// async global->LDS, 16B per lane (dest = wave-uniform base + lane*16)
__device__ __forceinline__ void gload16(const void* g, void* l) {
    __builtin_amdgcn_global_load_lds(
        (const __attribute__((address_space(1))) unsigned int*)g,
        (__attribute__((address_space(3))) unsigned int*)l, 16, 0, 0);
}

// ---------------------------------------------------------------------------
// Guard-fail fill (encodes ws_size MB as output on too-small workspace)
// ---------------------------------------------------------------------------
__global__ __launch_bounds__(256) void fill_kernel(float* __restrict__ out,
                                                   int n, float val)
{
    const int i = blockIdx.x * 256 + threadIdx.x;
    if (i < n) out[i] = val;
}

// ---------------------------------------------------------------------------
// RMSNorm: one block per row of D=1024; outputs fp16 xn.
// ---------------------------------------------------------------------------
__global__ __launch_bounds__(256) void rmsnorm_kernel(
    const float* __restrict__ x, const float* __restrict__ scale,
    f16_t* __restrict__ xn)
{
    const int row = blockIdx.x;
    const int tid = threadIdx.x;
    const float4 v = reinterpret_cast<const float4*>(x + (size_t)row * DDIM)[tid];
    float ss = v.x*v.x + v.y*v.y + v.z*v.z + v.w*v.w;
    #pragma unroll
    for (int off = 32; off > 0; off >>= 1)
        ss += __shfl_down(ss, off, 64);
    __shared__ float red[4];
    if ((tid & 63) == 0) red[tid >> 6] = ss;
    __syncthreads();
    ss = red[0] + red[1] + red[2] + red[3];
    const float inv = rsqrtf(ss * (1.0f / DDIM) + EPS);
    const float4 sc = reinterpret_cast<const float4*>(scale)[tid];
    f16x4_t o;
    o.x = (f16_t)(v.x * inv * sc.x);
    o.y = (f16_t)(v.y * inv * sc.y);
    o.z = (f16_t)(v.z * inv * sc.z);
    o.w = (f16_t)(v.w * inv * sc.w);
    reinterpret_cast<f16x4_t*>(xn + (size_t)row * DDIM)[tid] = o;
}

// ---------------------------------------------------------------------------
// transpose1: W[K][N] f32 -> WT[N][K] f16 (for wo).
// ---------------------------------------------------------------------------
__global__ __launch_bounds__(256) void transpose1_kernel(
    const float* __restrict__ W, f16_t* __restrict__ dst)
{
    const int K = DDIM, N = DDIM;
    __shared__ float t[32][33];
    const int kb = blockIdx.y * 32;
    const int nb = blockIdx.x * 32;
    const int r  = threadIdx.x >> 3;
    const int c0 = (threadIdx.x & 7) << 2;
    const float4 v = *reinterpret_cast<const float4*>(&W[(size_t)(kb + r) * N + nb + c0]);
    t[r][c0 + 0] = v.x; t[r][c0 + 1] = v.y; t[r][c0 + 2] = v.z; t[r][c0 + 3] = v.w;
    __syncthreads();
    f16x4_t o;
    o.x = (f16_t)t[c0 + 0][r];
    o.y = (f16_t)t[c0 + 1][r];
    o.z = (f16_t)t[c0 + 2][r];
    o.w = (f16_t)t[c0 + 3][r];
    *reinterpret_cast<f16x4_t*>(&dst[(size_t)(nb + r) * K + kb + c0]) = o;
}

// ---------------------------------------------------------------------------
// transpose_pair: two W[K][N] f32 -> WT with INTERLEAVED rows:
// WT[2n][k] = W0[k][n], WT[2n+1][k] = W1[k][n]. Used for (wq,wg), (wk,wv)
// so the GEMM epilogue sees the pair in adjacent lanes (mode-4 pattern).
// ---------------------------------------------------------------------------
__global__ __launch_bounds__(256) void transpose_pair_kernel(
    const float* __restrict__ W0, const float* __restrict__ W1,
    f16_t* __restrict__ WT)
{
    const int K = DDIM, N = DDIM;
    __shared__ float t0[32][33];
    __shared__ float t1[32][33];
    const int kb = blockIdx.y * 32;
    const int nb = blockIdx.x * 32;
    const int r  = threadIdx.x >> 3;
    const int c0 = (threadIdx.x & 7) << 2;
    const float4 v0 = *reinterpret_cast<const float4*>(&W0[(size_t)(kb + r) * N + nb + c0]);
    const float4 v1 = *reinterpret_cast<const float4*>(&W1[(size_t)(kb + r) * N + nb + c0]);
    t0[r][c0 + 0] = v0.x; t0[r][c0 + 1] = v0.y; t0[r][c0 + 2] = v0.z; t0[r][c0 + 3] = v0.w;
    t1[r][c0 + 0] = v1.x; t1[r][c0 + 1] = v1.y; t1[r][c0 + 2] = v1.z; t1[r][c0 + 3] = v1.w;
    __syncthreads();
    const int rr  = threadIdx.x >> 2;        // output row in block: 0..63
    const int cc0 = (threadIdx.x & 3) << 3;  // 0,8,16,24
    const int n   = rr >> 1;                 // source col within tile
    f16x8_t o;
    if (rr & 1) {
        #pragma unroll
        for (int e = 0; e < 8; ++e) o[e] = (f16_t)t1[cc0 + e][n];
    } else {
        #pragma unroll
        for (int e = 0; e < 8; ++e) o[e] = (f16_t)t0[cc0 + e][n];
    }
    *reinterpret_cast<f16x8_t*>(&WT[(size_t)(2 * nb + rr) * K + kb + cc0]) = o;
}

// ---------------------------------------------------------------------------
// Weight prep for wa: W[K][2048] f32 -> WTa[n][K] f16 with INTERLEAVED rows:
// output row n corresponds to original column (n>>1) + (n&1)*1024.
// ---------------------------------------------------------------------------
__global__ __launch_bounds__(256) void transpose_a_kernel(
    const float* __restrict__ W, f16_t* __restrict__ WT)
{
    const int K = DDIM, N = 2 * DDIM;
    __shared__ float t[32][33];
    const int kb = blockIdx.y * 32;
    const int nb = blockIdx.x * 32;
    const int r  = threadIdx.x >> 3;
    const int c0 = (threadIdx.x & 7) << 2;
    const int base = (c0 < 16) ? ((nb >> 1) + c0) : (DDIM + (nb >> 1) + c0 - 16);
    const float4 v = *reinterpret_cast<const float4*>(&W[(size_t)(kb + r) * N + base]);
    t[r][c0 + 0] = v.x; t[r][c0 + 1] = v.y; t[r][c0 + 2] = v.z; t[r][c0 + 3] = v.w;
    __syncthreads();
    const int rr  = threadIdx.x >> 3;
    const int cc0 = (threadIdx.x & 7) << 2;
    const int ctile = (rr >> 1) + (rr & 1) * 16;
    f16x4_t o;
    o.x = (f16_t)t[cc0 + 0][ctile];
    o.y = (f16_t)t[cc0 + 1][ctile];
    o.z = (f16_t)t[cc0 + 2][ctile];
    o.w = (f16_t)t[cc0 + 3][ctile];
    *reinterpret_cast<f16x4_t*>(&WT[(size_t)(nb + rr) * K + kb + cc0]) = o;
}

// ---------------------------------------------------------------------------
// fp16 MFMA GEMM (m97 pattern, R4-proven core): C[M,N] = A[M,K] @ BT[N,K]^T
// 128x128 tile, BK=32, 256 threads = 4 waves, each wave 64x64 (4x4 MFMA tiles).
//  - T1 XCD-aware bijective block swizzle (R4: FETCH 142->94 MB)
//  - quad-XOR LDS swizzle (R4: bank conflicts 12.6M -> 0)
// MODE 0: C(f32)  = A@B                               (final GEMM)
// MODE 4: a-polar fused -> f16: val*sigmoid(|a|)/|a|  (interleaved re/im)
// MODE 6: pair-product epilogue. BT rows interleave two weights; adjacent
//         lanes hold (X=even col, Y=odd col) of one output channel:
//         bn<2048: qsg = X*silu(Y) -> Cv (q,g pair);  else kv = X*Y -> Cv2.
//         One f16 per pair, written by even lanes at [row][paircol].
// ---------------------------------------------------------------------------
template <int MODE>
__global__ __launch_bounds__(256, 2) void mfma_gemm_kernel(
    const f16_t* __restrict__ A, const f16_t* __restrict__ BT,
    void* __restrict__ Cv, void* __restrict__ Cv2, void* __restrict__ Cv3,
    int M, int N, int K)
{
    __shared__ __align__(16) f16_t As[128 * 32];   // [m][k], 64B rows
    __shared__ __align__(16) f16_t Bs[128 * 32];   // [n][k]

    const int tid  = threadIdx.x;
    const int wave = tid >> 6;
    const int lane = tid & 63;

    // ---- T1: XCD-aware bijective block swizzle ---------------------------
    const int gx  = gridDim.x;
    const int nwg = gx * gridDim.y;
    const int lid = blockIdx.y * gx + blockIdx.x;
    const int cpx = nwg >> 3;                  // nwg % 8 == 0 for all grids
    const int vid = (lid & 7) * cpx + (lid >> 3);
    const int bm = (vid / gx) * 128;
    const int bn = (vid % gx) * 128;

    const int wm = (wave & 1) * 64;
    const int wn = (wave >> 1) * 64;

    // ---- staging: quad-contiguous, within-quad chunk XOR -----------------
    const int sr = tid >> 2;
    const int sc = (((tid & 3) ^ ((tid >> 3) & 3)) << 3);   // swizzled chunk
    const f16_t* Ag = A  + (size_t)(bm + sr) * K + sc;
    const f16_t* Bg = BT + (size_t)(bn + sr) * K + sc;
    f16_t* Al0 = As + tid * 8;
    f16_t* Al1 = As + 64 * 32 + tid * 8;
    f16_t* Bl0 = Bs + tid * 8;
    f16_t* Bl1 = Bs + 64 * 32 + tid * 8;
    const size_t rowskip = (size_t)64 * K;

    f32x4_t acc[4][4] = {};

    // ---- frag read: same XOR key ((row>>1)&3 == (lane>>1)&3) -------------
    const int fm = lane & 15;
    const int kh = (((lane >> 4) ^ ((lane >> 1) & 3)) << 3);

    for (int kt = 0; kt < K; kt += 32) {
        gload16(Ag + kt, Al0);
        gload16(Ag + rowskip + kt, Al1);
        gload16(Bg + kt, Bl0);
        gload16(Bg + rowskip + kt, Bl1);
        __syncthreads();

        f16x8_t af[4], bfr[4];
        #pragma unroll
        for (int i = 0; i < 4; ++i)
            af[i] = *reinterpret_cast<const f16x8_t*>(&As[(wm + i * 16 + fm) * 32 + kh]);
        #pragma unroll
        for (int j = 0; j < 4; ++j)
            bfr[j] = *reinterpret_cast<const f16x8_t*>(&Bs[(wn + j * 16 + fm) * 32 + kh]);
        #pragma unroll
        for (int i = 0; i < 4; ++i)
            #pragma unroll
            for (int j = 0; j < 4; ++j)
                acc[i][j] = __builtin_amdgcn_mfma_f32_16x16x32_f16(
                    af[i], bfr[j], acc[i][j], 0, 0, 0);
        __syncthreads();
    }

    // epilogue: D row=(lane>>4)*4+reg, col=lane&15  (m89/m91-verified)
    const int erow = (lane >> 4) << 2;
    const int ecol = lane & 15;
    #pragma unroll
    for (int i = 0; i < 4; ++i) {
        #pragma unroll
        for (int j = 0; j < 4; ++j) {
            const int row0 = bm + wm + i * 16 + erow;
            const int col  = bn + wn + j * 16 + ecol;
            #pragma unroll
            for (int rg = 0; rg < 4; ++rg) {
                const size_t idx = (size_t)(row0 + rg) * N + col;
                const float val = acc[i][j][rg];
                if (MODE == 0) {
                    ((float*)Cv)[idx] = val;
                } else if (MODE == 4) {
                    // adjacent lanes hold (re,im) of one channel
                    const float par = __shfl_xor(val, 1, 64);
                    const float re = (lane & 1) ? par : val;
                    const float im = (lane & 1) ? val : par;
                    const float r = sqrtf(re * re + im * im);
                    float outv;
                    if (r > 0.0f) {
                        const float sg = 1.0f / (1.0f + __expf(-r));
                        outv = val * (sg / r);
                    } else {
                        outv = (lane & 1) ? 0.0f : 0.5f;
                    }
                    ((f16_t*)Cv)[idx] = (f16_t)outv;
                } else {  // MODE 6: pair-product
                    const float par = __shfl_xor(val, 1, 64);
                    const float X = (lane & 1) ? par : val;   // even col (q or k)
                    const float Y = (lane & 1) ? val : par;   // odd col  (g or v)
                    float outv;
                    if (bn < 2048) outv = X * (Y / (1.0f + __expf(-Y)));  // q*silu(g)
                    else           outv = X * Y;                          // k*v
                    if (!(lane & 1)) {
                        f16_t* dst = (bn < 2048) ? (f16_t*)Cv : (f16_t*)Cv2;
                        const int paircol = (((bn & 2047) + wn + j * 16 + ecol) >> 1);
                        dst[(size_t)(row0 + rg) * DDIM + paircol] = (f16_t)outv;
                    }
                }
            }
        }
    }
}

// ---------------------------------------------------------------------------
// Scan phase 1 (x2 channels/thread): per-(b,chunk,d-pair) local scan;
// emit (A_prod, H_local) float4 per channel. a layout: [m][d] f16x2 (re,im).
// ---------------------------------------------------------------------------
__global__ __launch_bounds__(256) void scan1_kernel(
    const f16x2_t* __restrict__ a2, const f16_t* __restrict__ kvb,
    float4* __restrict__ state)
{
    const int t = blockIdx.x * 256 + threadIdx.x;   // B*NCHUNK*512
    const int d2 = (t & 511) << 1;
    const int c = (t >> 9) & (NCHUNK - 1);
    const int b = t >> 15;
    size_t base  = ((size_t)(b * SDIM + c * LCHUNK)) * DDIM + d2;
    float Ar0 = 1.0f, Ai0 = 0.0f, Hr0 = 0.0f, Hi0 = 0.0f;
    float Ar1 = 1.0f, Ai1 = 0.0f, Hr1 = 0.0f, Hi1 = 0.0f;
    for (int s = 0; s < LCHUNK; ++s) {
        const f16x4_t av = *reinterpret_cast<const f16x4_t*>(&a2[base]);   // 2 ch
        const f16x2_t kv2 = *reinterpret_cast<const f16x2_t*>(&kvb[base]);
        {
            const float ar = (float)av.x, ai = (float)av.y, kv = (float)kv2.x;
            const float hr = ar * Hr0 - ai * Hi0 + kv;
            const float hi = ar * Hi0 + ai * Hr0;
            Hr0 = hr; Hi0 = hi;
            const float nr = ar * Ar0 - ai * Ai0;
            const float ni = ar * Ai0 + ai * Ar0;
            Ar0 = nr; Ai0 = ni;
        }
        {
            const float ar = (float)av.z, ai = (float)av.w, kv = (float)kv2.y;
            const float hr = ar * Hr1 - ai * Hi1 + kv;
            const float hi = ar * Hi1 + ai * Hr1;
            Hr1 = hr; Hi1 = hi;
            const float nr = ar * Ar1 - ai * Ai1;
            const float ni = ar * Ai1 + ai * Ar1;
            Ar1 = nr; Ai1 = ni;
        }
        base += DDIM;
    }
    const size_t st = ((size_t)(b * NCHUNK + c)) * DDIM + d2;
    state[st]     = make_float4(Ar0, Ai0, Hr0, Hi0);
    state[st + 1] = make_float4(Ar1, Ai1, Hr1, Hi1);
}

// ---------------------------------------------------------------------------
// Scan phase 2: wave-parallel chunk combine. Lane c holds chunk c's state;
// 6-step Hillis-Steele inclusive scan of (A,H)∘, then exclusive-shift -> carry.
// ---------------------------------------------------------------------------
__global__ __launch_bounds__(256) void scan2_kernel(
    const float4* __restrict__ state, float2* __restrict__ carry)
{
    const int t = blockIdx.x * 256 + threadIdx.x;   // B*D*64 threads
    const int c = t & 63;            // chunk index = lane
    const int ch = t >> 6;           // channel: b*1024+d
    const int d = ch & 1023;
    const int b = ch >> 10;
    const size_t idx = ((size_t)(b * NCHUNK + c)) * DDIM + d;
    const float4 st = state[idx];
    float Ar = st.x, Ai = st.y, Hr = st.z, Hi = st.w;
    #pragma unroll
    for (int off = 1; off < 64; off <<= 1) {
        const float pAr = __shfl_up(Ar, off, 64);
        const float pAi = __shfl_up(Ai, off, 64);
        const float pHr = __shfl_up(Hr, off, 64);
        const float pHi = __shfl_up(Hi, off, 64);
        if (c >= off) {
            // compose(earlier=(pA,pH), current=(A,H)): A·pA, A·pH + H
            const float nHr = Ar * pHr - Ai * pHi + Hr;
            const float nHi = Ar * pHi + Ai * pHr + Hi;
            const float nAr = Ar * pAr - Ai * pAi;
            const float nAi = Ar * pAi + Ai * pAr;
            Ar = nAr; Ai = nAi; Hr = nHr; Hi = nHi;
        }
    }
    // exclusive prefix: carry into chunk c = inclusive H at chunk c-1
    const float eHr = __shfl_up(Hr, 1, 64);
    const float eHi = __shfl_up(Hi, 1, 64);
    carry[idx] = make_float2(c == 0 ? 0.0f : eHr, c == 0 ? 0.0f : eHi);
}

// ---------------------------------------------------------------------------
// Scan phase 3 (x2 channels/thread): re-scan with carry;
// y(f16) = qsg * Re(h), written IN-PLACE over kv.  (qsg = q*silu(g), fused
// in the mode-6 GEMM epilogue.)
// ---------------------------------------------------------------------------
__global__ __launch_bounds__(256) void scan3_kernel(
    const f16x2_t* __restrict__ a2, f16_t* __restrict__ kvb,
    const f16_t* __restrict__ qsgb, const float2* __restrict__ carry)
{
    const int t = blockIdx.x * 256 + threadIdx.x;   // B*NCHUNK*512
    const int d2 = (t & 511) << 1;
    const int c = (t >> 9) & (NCHUNK - 1);
    const int b = t >> 15;
    size_t base  = ((size_t)(b * SDIM + c * LCHUNK)) * DDIM + d2;
    const size_t st = ((size_t)(b * NCHUNK + c)) * DDIM + d2;
    const float2 h0a = carry[st];
    const float2 h0b = carry[st + 1];
    float Hr0 = h0a.x, Hi0 = h0a.y;
    float Hr1 = h0b.x, Hi1 = h0b.y;
    for (int s = 0; s < LCHUNK; ++s) {
        const f16x4_t av = *reinterpret_cast<const f16x4_t*>(&a2[base]);
        const f16x2_t kv2 = *reinterpret_cast<const f16x2_t*>(&kvb[base]);
        const f16x2_t qs2 = *reinterpret_cast<const f16x2_t*>(&qsgb[base]);
        f16x2_t y;
        {
            const float ar = (float)av.x, ai = (float)av.y, kv = (float)kv2.x;
            const float hr = ar * Hr0 - ai * Hi0 + kv;
            const float hi = ar * Hi0 + ai * Hr0;
            Hr0 = hr; Hi0 = hi;
            y.x = (f16_t)((float)qs2.x * hr);
        }
        {
            const float ar = (float)av.z, ai = (float)av.w, kv = (float)kv2.y;
            const float hr = ar * Hr1 - ai * Hi1 + kv;
            const float hi = ar * Hi1 + ai * Hr1;
            Hr1 = hr; Hi1 = hi;
            y.y = (f16_t)((float)qs2.y * hr);
        }
        *reinterpret_cast<f16x2_t*>(&kvb[base]) = y;
        base += DDIM;
    }
}

// ---------------------------------------------------------------------------
// kernel_launch
//
// Workspace layout (149 MB):
//   xn:  [SZ f16]   33.5MB — A operand; scan `state` (4MB) overlaps after death
//   kv:  [SZ f16]   33.5MB — kv=k*v (fused GEMM), then y (in-place in scan3)
//   a:   [SZ f16x2] 67MB   — interleaved (re,im) channel pairs
//   WT:  [7*WSZ f16] 14MB  — slots: 0..1=qg(interleaved) 2..3=kv(interleaved)
//        4..5=a(interleaved) 6=o; `carry` (2MB) overlaps dead slot 0
// qsg (f16) lives in the first half of d_out until the final GEMM overwrites it.
// ---------------------------------------------------------------------------
extern "C" void kernel_launch(void* const* d_in, const int* in_sizes, int n_in,
                              void* d_out, int out_size, void* d_ws, size_t ws_size,
                              hipStream_t stream)
{
    const float* x        = (const float*)d_in[0];
    const float* wq       = (const float*)d_in[1];
    const float* wk       = (const float*)d_in[2];
    const float* wv       = (const float*)d_in[3];
    const float* wa       = (const float*)d_in[4];
    const float* wg       = (const float*)d_in[5];
    const float* wo       = (const float*)d_in[6];
    const float* rms_scale= (const float*)d_in[7];
    float* out = (float*)d_out;

    const size_t SZ = (size_t)MROWS * DDIM;   // 16,777,216 elements
    const size_t WSZ = (size_t)DDIM * DDIM;   // 1,048,576
    char* ws = (char*)d_ws;
    f16_t*   xn   = (f16_t*)ws;                        // SZ f16
    f16_t*   kv   = (f16_t*)(ws + SZ * 2);             // SZ f16
    f16x2_t* abuf = (f16x2_t*)(ws + SZ * 4);           // SZ f16x2
    f16_t*   WT   = (f16_t*)(ws + SZ * 8);             // 7*WSZ f16
    f16_t* WTqg = WT;                // slots 0..1 (wq/wg interleaved)
    f16_t* WTkv = WT + 2 * WSZ;      // slots 2..3 (wk/wv interleaved)
    f16_t* WTa  = WT + 4 * WSZ;      // slots 4..5 (wa interleaved halves)
    f16_t* WTo  = WT + 6 * WSZ;      // slot 6
    float4* state = (float4*)xn;     // overlaps dead xn (4MB)
    float2* carry = (float2*)WT;     // overlaps dead WTqg slot 0 (2MB)

    f16_t* qsgb = (f16_t*)d_out;     // qsg f16 in first half of d_out

    const size_t needed = SZ * 8 + 7 * WSZ * 2;
    if (ws_size < needed) {
        const float marker = (float)(ws_size >> 20);
        fill_kernel<<<(out_size + 255) / 256, 256, 0, stream>>>(out, out_size, marker);
        return;
    }

    // 1. RMSNorm -> f16 xn
    rmsnorm_kernel<<<MROWS, 256, 0, stream>>>(x, rms_scale, xn);

    // 2. Weight prep (4 small launches)
    dim3 tblk(256);
    dim3 tg(DDIM / 32, DDIM / 32);
    transpose_pair_kernel<<<tg, tblk, 0, stream>>>(wq, wg, WTqg);
    transpose_pair_kernel<<<tg, tblk, 0, stream>>>(wk, wv, WTkv);
    transpose1_kernel<<<tg, tblk, 0, stream>>>(wo, WTo);
    dim3 tga(2 * DDIM / 32, DDIM / 32);
    transpose_a_kernel<<<tga, tblk, 0, stream>>>(wa, WTa);

    // 3. Projections
    //    mode-6: N=4096 (qg + kv interleaved) -> qsg (d_out) and kv=k*v (ws)
    //    mode-4: N=2048 -> a (polar-fused)
    dim3 blk(256);
    dim3 g6(4 * DDIM / 128, MROWS / 128);     // (32,128)
    dim3 g2(2 * DDIM / 128, MROWS / 128);     // (16,128)
    dim3 g1(DDIM / 128, MROWS / 128);         // (8,128)
    mfma_gemm_kernel<6><<<g6, blk, 0, stream>>>(xn, WT,  qsgb, kv, nullptr, MROWS, 4 * DDIM, DDIM);
    mfma_gemm_kernel<4><<<g2, blk, 0, stream>>>(xn, WTa, abuf, nullptr, nullptr, MROWS, 2 * DDIM, DDIM);

    // 4. chunked complex scan (x2-channel vectorized phases 1 & 3)
    const int nscan2 = BDIM * NCHUNK * 512;   // 131072 threads
    const int nscan  = BDIM * NCHUNK * DDIM;  // 262144 threads (phase 2)
    scan1_kernel<<<nscan2 / 256, 256, 0, stream>>>(abuf, kv, state);
    scan2_kernel<<<nscan / 256, 256, 0, stream>>>(state, carry);
    scan3_kernel<<<nscan2 / 256, 256, 0, stream>>>(abuf, kv, qsgb, carry);

    // 5. out = y @ wo   (y lives in kv buffer)
    mfma_gemm_kernel<0><<<g1, blk, 0, stream>>>(kv, WTo, out, nullptr, nullptr, MROWS, DDIM, DDIM);
}